// Round 6
// baseline (394.982 us; speedup 1.0000x reference)
//
#include <hip/hip_runtime.h>
#include <cstddef>
#include <cstdint>

#define N_NODES 50000
#define N_EDGES 800000
#define NP 50048   // 391 * 128, padded row count
static constexpr float BN_EPS = 1e-5f;

typedef unsigned short u16;
typedef short bf16x8 __attribute__((ext_vector_type(8)));
typedef float f32x4 __attribute__((ext_vector_type(4)));

// ---------------- helpers ----------------
__device__ inline u16 f2bf(float f) {
    union { float f; unsigned u; } v; v.f = f;
    unsigned r = v.u + 0x7fffu + ((v.u >> 16) & 1u);
    return (u16)(r >> 16);
}
__device__ inline unsigned pack2(float a, float b) {
    return (unsigned)f2bf(a) | ((unsigned)f2bf(b) << 16);
}
__device__ inline void addbf2(unsigned u, float& lo, float& hi) {
    union { unsigned u; float f; } t;
    t.u = u << 16; lo += t.f;
    t.u = u & 0xFFFF0000u; hi += t.f;
}
__device__ inline void bf2(unsigned u, float& lo, float& hi) {
    union { unsigned u; float f; } t;
    t.u = u << 16; lo = t.f;
    t.u = u & 0xFFFF0000u; hi = t.f;
}

// ---------------- utility: zero fill ----------------
__global__ void fill_zero(float* __restrict__ p, int n4) {
    float4* p4 = (float4*)p;
    for (int i = blockIdx.x * blockDim.x + threadIdx.x; i < n4; i += gridDim.x * blockDim.x)
        p4[i] = make_float4(0.f, 0.f, 0.f, 0.f);
}

// ---------------- fp32 -> bf16 convert ----------------
__global__ __launch_bounds__(256) void f32_to_bf16(const float* __restrict__ in,
                                                   u16* __restrict__ out, int n8) {
    const float4* in4 = (const float4*)in;
    uint4* out4 = (uint4*)out;
    for (int i = blockIdx.x * blockDim.x + threadIdx.x; i < n8; i += gridDim.x * blockDim.x) {
        float4 a = in4[2 * i], b = in4[2 * i + 1];
        uint4 u;
        u.x = pack2(a.x, a.y); u.y = pack2(a.z, a.w);
        u.z = pack2(b.x, b.y); u.w = pack2(b.z, b.w);
        out4[i] = u;
    }
}

// ---------------- CSR build ----------------
__global__ void deg_count(const int* __restrict__ dst, int* __restrict__ deg, int E) {
    int i = blockIdx.x * blockDim.x + threadIdx.x;
    if (i < E) atomicAdd(&deg[dst[i]], 1);
}

__global__ __launch_bounds__(256) void scan_phase1(const int* __restrict__ deg,
                                                   int* __restrict__ rowptr,
                                                   int* __restrict__ blocksum, int n) {
    __shared__ int s[256];
    const int t = threadIdx.x;
    const int i = blockIdx.x * 256 + t;
    int d = (i < n) ? deg[i] : 0;
    s[t] = d;
    __syncthreads();
    for (int off = 1; off < 256; off <<= 1) {
        int v = (t >= off) ? s[t - off] : 0;
        __syncthreads();
        s[t] += v;
        __syncthreads();
    }
    if (i < n) rowptr[i] = s[t] - d;
    if (t == 255) blocksum[blockIdx.x] = s[t];
}

__global__ __launch_bounds__(256) void scan_phase2(int* __restrict__ blocksum,
                                                   int* __restrict__ rowptr, int nb, int n) {
    __shared__ int s[256];
    const int t = threadIdx.x;
    int d = (t < nb) ? blocksum[t] : 0;
    s[t] = d;
    __syncthreads();
    for (int off = 1; off < 256; off <<= 1) {
        int v = (t >= off) ? s[t - off] : 0;
        __syncthreads();
        s[t] += v;
        __syncthreads();
    }
    if (t < nb) blocksum[t] = s[t] - d;
    if (t == 255) rowptr[n] = s[t];
}

__global__ __launch_bounds__(256) void scan_phase3(int* __restrict__ rowptr,
                                                   const int* __restrict__ blocksum,
                                                   const int* __restrict__ deg,
                                                   float* __restrict__ inv, int n) {
    int i = blockIdx.x * 256 + threadIdx.x;
    if (i >= n) return;
    rowptr[i] += blocksum[i >> 8];
    inv[i] = 1.0f / fmaxf((float)deg[i], 1.0f);
}

__global__ void csr_fill(const int* __restrict__ src, const int* __restrict__ dst,
                         const int* __restrict__ rowptr, int* __restrict__ cursor,
                         int* __restrict__ csr, int E) {
    int e = blockIdx.x * blockDim.x + threadIdx.x;
    if (e >= E) return;
    int d = dst[e];
    int p = atomicAdd(&cursor[d], 1);
    csr[rowptr[d] + p] = src[e];
}

// ---------------- gather-mean (layer 1: bf16 in, bf16 out, fp32 accumulate) ----------------
template <int KH>
__global__ __launch_bounds__(256) void gather_mean_bf16(const u16* __restrict__ F,
                                                        const int* __restrict__ rowptr,
                                                        const int* __restrict__ csr,
                                                        const float* __restrict__ inv,
                                                        u16* __restrict__ Sout, int N) {
    constexpr int CG = KH / 8;
    constexpr int NPB = 256 / CG;
    const int c = threadIdx.x % CG;
    const int node = blockIdx.x * NPB + threadIdx.x / CG;
    if (node >= N) return;
    const uint4* F4 = (const uint4*)F;
    float a0 = 0, a1 = 0, a2 = 0, a3 = 0, a4 = 0, a5 = 0, a6 = 0, a7 = 0;
    const int beg = rowptr[node], end = rowptr[node + 1];
    int k = beg;
    for (; k + 3 < end; k += 4) {
        uint4 v0 = F4[(size_t)csr[k] * CG + c];
        uint4 v1 = F4[(size_t)csr[k + 1] * CG + c];
        uint4 v2 = F4[(size_t)csr[k + 2] * CG + c];
        uint4 v3 = F4[(size_t)csr[k + 3] * CG + c];
        addbf2(v0.x, a0, a1); addbf2(v0.y, a2, a3); addbf2(v0.z, a4, a5); addbf2(v0.w, a6, a7);
        addbf2(v1.x, a0, a1); addbf2(v1.y, a2, a3); addbf2(v1.z, a4, a5); addbf2(v1.w, a6, a7);
        addbf2(v2.x, a0, a1); addbf2(v2.y, a2, a3); addbf2(v2.z, a4, a5); addbf2(v2.w, a6, a7);
        addbf2(v3.x, a0, a1); addbf2(v3.y, a2, a3); addbf2(v3.z, a4, a5); addbf2(v3.w, a6, a7);
    }
    for (; k < end; ++k) {
        uint4 v0 = F4[(size_t)csr[k] * CG + c];
        addbf2(v0.x, a0, a1); addbf2(v0.y, a2, a3); addbf2(v0.z, a4, a5); addbf2(v0.w, a6, a7);
    }
    const float w = inv[node];
    uint4 u;
    u.x = pack2(a0 * w, a1 * w); u.y = pack2(a2 * w, a3 * w);
    u.z = pack2(a4 * w, a5 * w); u.w = pack2(a6 * w, a7 * w);
    ((uint4*)Sout)[(size_t)node * CG + c] = u;
}

// ---------------- gather-add (layers 2,3): Hpre = mean-agg(P) + Q, PQ = [P|Q] rows ----------------
template <int D>
__global__ __launch_bounds__(256) void gather_add_bf16(const u16* __restrict__ PQ,
                                                       const int* __restrict__ rowptr,
                                                       const int* __restrict__ csr,
                                                       const float* __restrict__ inv,
                                                       u16* __restrict__ Hpre, int N) {
    constexpr int CG = D / 8;      // threads per node
    constexpr int NPB = 256 / CG;
    constexpr int RS4 = D / 4;     // uint4 per [P|Q] row
    const int c = threadIdx.x % CG;
    const int node = blockIdx.x * NPB + threadIdx.x / CG;
    if (node >= N) return;
    const uint4* PQ4 = (const uint4*)PQ;
    float a0 = 0, a1 = 0, a2 = 0, a3 = 0, a4 = 0, a5 = 0, a6 = 0, a7 = 0;
    const int beg = rowptr[node], end = rowptr[node + 1];
    int k = beg;
    for (; k + 3 < end; k += 4) {
        uint4 v0 = PQ4[(size_t)csr[k] * RS4 + c];
        uint4 v1 = PQ4[(size_t)csr[k + 1] * RS4 + c];
        uint4 v2 = PQ4[(size_t)csr[k + 2] * RS4 + c];
        uint4 v3 = PQ4[(size_t)csr[k + 3] * RS4 + c];
        addbf2(v0.x, a0, a1); addbf2(v0.y, a2, a3); addbf2(v0.z, a4, a5); addbf2(v0.w, a6, a7);
        addbf2(v1.x, a0, a1); addbf2(v1.y, a2, a3); addbf2(v1.z, a4, a5); addbf2(v1.w, a6, a7);
        addbf2(v2.x, a0, a1); addbf2(v2.y, a2, a3); addbf2(v2.z, a4, a5); addbf2(v2.w, a6, a7);
        addbf2(v3.x, a0, a1); addbf2(v3.y, a2, a3); addbf2(v3.z, a4, a5); addbf2(v3.w, a6, a7);
    }
    for (; k < end; ++k) {
        uint4 v0 = PQ4[(size_t)csr[k] * RS4 + c];
        addbf2(v0.x, a0, a1); addbf2(v0.y, a2, a3); addbf2(v0.z, a4, a5); addbf2(v0.w, a6, a7);
    }
    const float w = inv[node];
    uint4 q = PQ4[(size_t)node * RS4 + D / 8 + c];
    float q0, q1, q2, q3, q4, q5, q6, q7;
    bf2(q.x, q0, q1); bf2(q.y, q2, q3); bf2(q.z, q4, q5); bf2(q.w, q6, q7);
    uint4 u;
    u.x = pack2(a0 * w + q0, a1 * w + q1);
    u.y = pack2(a2 * w + q2, a3 * w + q3);
    u.z = pack2(a4 * w + q4, a5 * w + q5);
    u.w = pack2(a6 * w + q6, a7 * w + q7);
    ((uint4*)Hpre)[(size_t)node * (D / 8) + c] = u;
}

// ---------------- weight prep ----------------
// layer 1: WT[n][k] = bf16([Wl;Wr]^T), concat along K
template <int KH, int NOUT>
__global__ __launch_bounds__(256) void wt_build(const float* __restrict__ Wl,
                                                const float* __restrict__ Wr,
                                                u16* __restrict__ WT) {
    constexpr int K = 2 * KH;
    int idx = blockIdx.x * 256 + threadIdx.x;
    if (idx >= NOUT * K) return;
    int n = idx / K, k = idx % K;
    float v = (k < KH) ? Wl[(size_t)k * NOUT + n] : Wr[(size_t)(k - KH) * NOUT + n];
    WT[idx] = f2bf(v);
}

// layers 2,3: WT[n][k] for n<D -> Wl, else Wr (concat along N -> output [P|Q])
template <int K, int D>
__global__ __launch_bounds__(256) void wt_build_cat(const float* __restrict__ Wl,
                                                    const float* __restrict__ Wr,
                                                    u16* __restrict__ WT) {
    int idx = blockIdx.x * 256 + threadIdx.x;
    if (idx >= 2 * D * K) return;
    int n = idx / K, k = idx % K;
    float v = (n < D) ? Wl[(size_t)k * D + n] : Wr[(size_t)k * D + (n - D)];
    WT[idx] = f2bf(v);
}

__global__ void bias_cat(const float* __restrict__ b, float* __restrict__ out, int half) {
    int j = blockIdx.x * blockDim.x + threadIdx.x;
    if (j < half) out[j] = 0.f;
    else if (j < 2 * half) out[j] = b[j - half];
}

// ---------------- MFMA GEMM: H = A @ W + b (opt. [S|X] concat-K, opt. fused BN stats) ----------------
template <int KH, int K, int NOUT, bool STATS>
__global__ __launch_bounds__(256, 1) void sage_gemm(const u16* __restrict__ S,
                                                    const u16* __restrict__ X,
                                                    const u16* __restrict__ WT,
                                                    const float* __restrict__ BL,
                                                    u16* __restrict__ Hb,
                                                    float* __restrict__ sums,
                                                    float* __restrict__ sumsq, int M) {
    constexpr int NK = K / 32;
    constexpr int FN = NOUT / 32;
    constexpr int BUFSZ = 4096 + NOUT * 32;
    __shared__ __align__(16) u16 lds[2][BUFSZ];
    const int t = threadIdx.x;
    const int wid = t >> 6, lane = t & 63;
    const int row0 = blockIdx.x * 128;
    const int wm = wid >> 1, wn = wid & 1;
    const int fr = lane & 15, fc = lane >> 4;

    const int swz8 = (((lane & 3) ^ ((lane >> 3) & 3)) * 8);

    auto stage = [&](int buf, int ks) {
        const int k0 = ks * 32;
        const u16* srcA;
        int kb;
        if (k0 < KH) { srcA = S; kb = k0; } else { srcA = X; kb = k0 - KH; }
#pragma unroll
        for (int jj = 0; jj < 2; ++jj) {
            int j = wid + jj * 4;
            const u16* g = srcA + (size_t)(row0 + j * 16 + (lane >> 2)) * KH + kb + swz8;
            __builtin_amdgcn_global_load_lds(
                (const __attribute__((address_space(1))) void*)g,
                (__attribute__((address_space(3))) void*)&lds[buf][j * 512], 16, 0, 0);
        }
#pragma unroll
        for (int jj = 0; jj < NOUT / 64; ++jj) {
            int j = wid * (NOUT / 64) + jj;
            const u16* gb = WT + (size_t)(j * 16 + (lane >> 2)) * K + k0 + swz8;
            __builtin_amdgcn_global_load_lds(
                (const __attribute__((address_space(1))) void*)gb,
                (__attribute__((address_space(3))) void*)&lds[buf][4096 + j * 512], 16, 0, 0);
        }
    };

    f32x4 acc[4][FN] = {};

    stage(0, 0);
    for (int ks = 0; ks < NK; ++ks) {
        __syncthreads();
        if (ks + 1 < NK) stage((ks + 1) & 1, ks + 1);
        const u16* A = &lds[ks & 1][0];
        const u16* B = &lds[ks & 1][4096];
        const int swr = (fr >> 1) & 3;
        const int kc = (fc ^ swr) * 8;
        bf16x8 a[4], b[FN];
#pragma unroll
        for (int fm = 0; fm < 4; ++fm)
            a[fm] = *(const bf16x8*)&A[(wm * 64 + fm * 16 + fr) * 32 + kc];
#pragma unroll
        for (int fn = 0; fn < FN; ++fn)
            b[fn] = *(const bf16x8*)&B[(wn * (NOUT / 2) + fn * 16 + fr) * 32 + kc];
#pragma unroll
        for (int fm = 0; fm < 4; ++fm)
#pragma unroll
            for (int fn = 0; fn < FN; ++fn)
                acc[fm][fn] = __builtin_amdgcn_mfma_f32_16x16x32_bf16(a[fm], b[fn], acc[fm][fn], 0, 0, 0);
    }

    const int cw = wn * (NOUT / 2);
    float bias[FN], s[FN], ss[FN];
#pragma unroll
    for (int fn = 0; fn < FN; ++fn) {
        bias[fn] = BL[cw + fn * 16 + fr];
        s[fn] = 0.f; ss[fn] = 0.f;
    }
#pragma unroll
    for (int fm = 0; fm < 4; ++fm) {
#pragma unroll
        for (int q = 0; q < 4; ++q) {
            int r = row0 + wm * 64 + fm * 16 + fc * 4 + q;
            if (r < M) {
#pragma unroll
                for (int fn = 0; fn < FN; ++fn) {
                    float h = acc[fm][fn][q] + bias[fn];
                    Hb[(size_t)r * NOUT + cw + fn * 16 + fr] = f2bf(h);
                    if constexpr (STATS) { s[fn] += h; ss[fn] += h * h; }
                }
            }
        }
    }
    if constexpr (STATS) {
#pragma unroll
        for (int fn = 0; fn < FN; ++fn) {
            float sv = s[fn], sq = ss[fn];
            sv += __shfl_xor(sv, 16); sv += __shfl_xor(sv, 32);
            sq += __shfl_xor(sq, 16); sq += __shfl_xor(sq, 32);
            if (fc == 0) {
                atomicAdd(&sums[cw + fn * 16 + fr], sv);
                atomicAdd(&sumsq[cw + fn * 16 + fr], sq);
            }
        }
    }
}

// ---------------- BN column stats (bf16 input) ----------------
template <int M>
__global__ __launch_bounds__(256) void col_stats_bf16(const u16* __restrict__ H,
                                                      float* __restrict__ sums,
                                                      float* __restrict__ sumsq, int nrows) {
    constexpr int G = 256 / M;
    int j = threadIdx.x % M;
    int rg = threadIdx.x / M;
    float s = 0.f, ss = 0.f;
    for (int r = blockIdx.x * G + rg; r < nrows; r += gridDim.x * G) {
        union { unsigned u; float f; } t;
        t.u = (unsigned)H[(size_t)r * M + j] << 16;
        s += t.f; ss += t.f * t.f;
    }
    atomicAdd(&sums[j], s);
    atomicAdd(&sumsq[j], ss);
}

// ---------------- BN finalize ----------------
template <int M>
__global__ void bn_finalize(const float* __restrict__ sums, const float* __restrict__ sumsq,
                            const float* __restrict__ g, const float* __restrict__ beta,
                            float* __restrict__ scale, float* __restrict__ shift, int nrows) {
    int j = threadIdx.x;
    if (j >= M) return;
    float mean = sums[j] / nrows;
    float var = fmaxf(sumsq[j] / nrows - mean * mean, 0.f);
    float sc = g[j] * rsqrtf(var + BN_EPS);
    scale[j] = sc;
    shift[j] = beta[j] - mean * sc;
}

// ---------------- BN apply + ReLU (bf16 -> bf16) ----------------
template <int M>
__global__ __launch_bounds__(256) void bn_relu_bf16(const u16* __restrict__ Hb,
                                                    const float* __restrict__ scale,
                                                    const float* __restrict__ shift,
                                                    u16* __restrict__ Ob, int n8) {
    const uint4* H4 = (const uint4*)Hb;
    uint4* O4 = (uint4*)Ob;
    const float4* sc4 = (const float4*)scale;
    const float4* sh4 = (const float4*)shift;
    for (int i = blockIdx.x * blockDim.x + threadIdx.x; i < n8; i += gridDim.x * blockDim.x) {
        int jg = i % (M / 8);
        uint4 v = H4[i];
        float4 s0 = sc4[jg * 2], s1 = sc4[jg * 2 + 1];
        float4 b0 = sh4[jg * 2], b1 = sh4[jg * 2 + 1];
        float x0, x1, x2, x3, x4, x5, x6, x7;
        bf2(v.x, x0, x1); bf2(v.y, x2, x3); bf2(v.z, x4, x5); bf2(v.w, x6, x7);
        x0 = fmaxf(fmaf(x0, s0.x, b0.x), 0.f);
        x1 = fmaxf(fmaf(x1, s0.y, b0.y), 0.f);
        x2 = fmaxf(fmaf(x2, s0.z, b0.z), 0.f);
        x3 = fmaxf(fmaf(x3, s0.w, b0.w), 0.f);
        x4 = fmaxf(fmaf(x4, s1.x, b1.x), 0.f);
        x5 = fmaxf(fmaf(x5, s1.y, b1.y), 0.f);
        x6 = fmaxf(fmaf(x6, s1.z, b1.z), 0.f);
        x7 = fmaxf(fmaf(x7, s1.w, b1.w), 0.f);
        uint4 u;
        u.x = pack2(x0, x1); u.y = pack2(x2, x3);
        u.z = pack2(x4, x5); u.w = pack2(x6, x7);
        O4[i] = u;
    }
}

// ---------------- head: out = H3 @ wh + bh ----------------
__global__ __launch_bounds__(256) void head_bf16_v2(const u16* __restrict__ H3,
                                                    const float* __restrict__ wh,
                                                    const float* __restrict__ bh,
                                                    float* __restrict__ out, int n) {
    int i = blockIdx.x * blockDim.x + threadIdx.x;
    if (i >= n) return;
    const uint4* h4 = (const uint4*)(H3 + (size_t)i * 64);
    float acc = bh[0];
#pragma unroll
    for (int c = 0; c < 8; ++c) {
        uint4 v = h4[c];
        float x0, x1, x2, x3, x4, x5, x6, x7;
        bf2(v.x, x0, x1); bf2(v.y, x2, x3); bf2(v.z, x4, x5); bf2(v.w, x6, x7);
        const float* w = wh + c * 8;
        acc += x0 * w[0] + x1 * w[1] + x2 * w[2] + x3 * w[3] +
               x4 * w[4] + x5 * w[5] + x6 * w[6] + x7 * w[7];
    }
    out[i] = acc;
}

// ---------------- launch ----------------
extern "C" void kernel_launch(void* const* d_in, const int* in_sizes, int n_in,
                              void* d_out, int out_size, void* d_ws, size_t ws_size,
                              hipStream_t stream) {
    const int N = N_NODES, E = N_EDGES;
    const float* x   = (const float*)d_in[0];
    const int*   ei  = (const int*)d_in[1];
    const int*   src = ei;
    const int*   dst = ei + E;
    const float* w1l = (const float*)d_in[2];
    const float* b1l = (const float*)d_in[3];
    const float* w1r = (const float*)d_in[4];
    const float* g1  = (const float*)d_in[5];
    const float* be1 = (const float*)d_in[6];
    const float* w2l = (const float*)d_in[7];
    const float* b2l = (const float*)d_in[8];
    const float* w2r = (const float*)d_in[9];
    const float* g2  = (const float*)d_in[10];
    const float* be2 = (const float*)d_in[11];
    const float* w3l = (const float*)d_in[12];
    const float* b3l = (const float*)d_in[13];
    const float* w3r = (const float*)d_in[14];
    const float* g3  = (const float*)d_in[15];
    const float* be3 = (const float*)d_in[16];
    const float* wh  = (const float*)d_in[17];
    const float* bh  = (const float*)d_in[18];
    float* out = (float*)d_out;

    // ---- workspace layout (256B-aligned regions) ----
    char* base = (char*)d_ws;
    size_t off = 0;
    auto alloc = [&](size_t bytes) -> void* {
        void* r = base + off;
        off += (bytes + 255) & ~(size_t)255;
        return r;
    };
    const int NB = (N + 255) / 256;  // 196 scan blocks
    int*   rowptr = (int*)alloc((N + 8) * sizeof(int));
    int*   csr    = (int*)alloc((size_t)E * sizeof(int));
    int*   ints2  = (int*)alloc(2 * (size_t)N * sizeof(int));  // deg_i | cursor
    int*   deg_i  = ints2;
    int*   cursor = ints2 + N;
    int*   bsum   = (int*)alloc(256 * sizeof(int));
    float* inv    = (float*)alloc(N * sizeof(float));
    u16*   xb     = (u16*)alloc((size_t)NP * 256 * 2);
    u16*   sB     = (u16*)alloc((size_t)NP * 256 * 2);
    u16*   h1b    = (u16*)alloc((size_t)NP * 256 * 2);
    u16*   h2b    = (u16*)alloc((size_t)NP * 128 * 2);
    u16*   h3b    = (u16*)alloc((size_t)NP * 64 * 2);
    u16*   hpre   = (u16*)alloc((size_t)NP * 256 * 2);   // layer1 pre-BN; layers 2/3 [P|Q]
    u16*   h2pre  = (u16*)alloc((size_t)NP * 128 * 2);
    u16*   h3pre  = (u16*)alloc((size_t)NP * 64 * 2);
    u16*   wt     = (u16*)alloc((size_t)256 * 512 * 2);
    float* stats  = (float*)alloc(1024 * sizeof(float));
    float* bias2  = (float*)alloc(256 * sizeof(float));
    float* bias3  = (float*)alloc(128 * sizeof(float));
    float* sums = stats, *sumsq = stats + 256, *scale = stats + 512, *shift = stats + 768;

    auto zero = [&](void* p, size_t nfloats) {
        int n4 = (int)(nfloats / 4);
        int blocks = (n4 + 255) / 256;
        if (blocks > 2048) blocks = 2048;
        fill_zero<<<blocks, 256, 0, stream>>>((float*)p, n4);
    };

    // ---- prep: x -> bf16 ----
    f32_to_bf16<<<2048, 256, 0, stream>>>(x, xb, N * 256 / 8);

    // ---- CSR build (3-phase parallel scan) ----
    zero(ints2, 2 * (size_t)N);
    deg_count<<<(E + 255) / 256, 256, 0, stream>>>(dst, deg_i, E);
    scan_phase1<<<NB, 256, 0, stream>>>(deg_i, rowptr, bsum, N);
    scan_phase2<<<1, 256, 0, stream>>>(bsum, rowptr, NB, N);
    scan_phase3<<<NB, 256, 0, stream>>>(rowptr, bsum, deg_i, inv, N);
    csr_fill<<<(E + 255) / 256, 256, 0, stream>>>(src, dst, rowptr, cursor, csr, E);

    const int MB = NP / 128;  // 391

    // ---- layer 1: agg-first (256 -> 256), fused [S|X] GEMM K=512, stats in epilogue ----
    gather_mean_bf16<256><<<(N * 32 + 255) / 256, 256, 0, stream>>>(xb, rowptr, csr, inv, sB, N);
    wt_build<256, 256><<<(256 * 512 + 255) / 256, 256, 0, stream>>>(w1l, w1r, wt);
    zero(sums, 512);
    sage_gemm<256, 512, 256, true><<<MB, 256, 0, stream>>>(sB, xb, wt, b1l, hpre, sums, sumsq, N);
    bn_finalize<256><<<1, 256, 0, stream>>>(sums, sumsq, g1, be1, scale, shift, N);
    bn_relu_bf16<256><<<2048, 256, 0, stream>>>(hpre, scale, shift, h1b, N * 256 / 8);

    // ---- layer 2: transform-first (256 -> 128) ----
    // [P|Q] = h1 @ [w2l | w2r] (+[0|b2l]);  h2pre = mean-agg(P) + Q
    wt_build_cat<256, 128><<<(256 * 256 + 255) / 256, 256, 0, stream>>>(w2l, w2r, wt);
    bias_cat<<<1, 256, 0, stream>>>(b2l, bias2, 128);
    sage_gemm<256, 256, 256, false><<<MB, 256, 0, stream>>>(h1b, h1b, wt, bias2, hpre, nullptr, nullptr, N);
    gather_add_bf16<128><<<(N * 16 + 255) / 256, 256, 0, stream>>>(hpre, rowptr, csr, inv, h2pre, N);
    zero(sums, 512);
    col_stats_bf16<128><<<128, 256, 0, stream>>>(h2pre, sums, sumsq, N);
    bn_finalize<128><<<1, 128, 0, stream>>>(sums, sumsq, g2, be2, scale, shift, N);
    bn_relu_bf16<128><<<2048, 256, 0, stream>>>(h2pre, scale, shift, h2b, N * 128 / 8);

    // ---- layer 3: transform-first (128 -> 64) ----
    wt_build_cat<128, 64><<<(128 * 128 + 255) / 256, 256, 0, stream>>>(w3l, w3r, wt);
    bias_cat<<<1, 128, 0, stream>>>(b3l, bias3, 64);
    sage_gemm<128, 128, 128, false><<<MB, 256, 0, stream>>>(h2b, h2b, wt, bias3, hpre, nullptr, nullptr, N);
    gather_add_bf16<64><<<(N * 8 + 255) / 256, 256, 0, stream>>>(hpre, rowptr, csr, inv, h3pre, N);
    zero(sums, 512);
    col_stats_bf16<64><<<128, 256, 0, stream>>>(h3pre, sums, sumsq, N);
    bn_finalize<64><<<1, 64, 0, stream>>>(sums, sumsq, g3, be3, scale, shift, N);
    bn_relu_bf16<64><<<2048, 256, 0, stream>>>(h3pre, scale, shift, h3b, N * 64 / 8);

    // ---- head ----
    head_bf16_v2<<<(N + 255) / 256, 256, 0, stream>>>(h3b, wh, bh, out, N);
}

// Round 7
// 333.891 us; speedup vs baseline: 1.1830x; 1.1830x over previous
//
#include <hip/hip_runtime.h>
#include <cstddef>
#include <cstdint>

#define N_NODES 50000
#define N_EDGES 800000
#define NP 50048   // 391 * 128, padded row count
static constexpr float BN_EPS = 1e-5f;

typedef unsigned short u16;
typedef short bf16x8 __attribute__((ext_vector_type(8)));
typedef float f32x4 __attribute__((ext_vector_type(4)));

// ---------------- helpers ----------------
__device__ inline u16 f2bf(float f) {
    union { float f; unsigned u; } v; v.f = f;
    unsigned r = v.u + 0x7fffu + ((v.u >> 16) & 1u);
    return (u16)(r >> 16);
}
__device__ inline unsigned pack2(float a, float b) {
    return (unsigned)f2bf(a) | ((unsigned)f2bf(b) << 16);
}
__device__ inline void addbf2(unsigned u, float& lo, float& hi) {
    union { unsigned u; float f; } t;
    t.u = u << 16; lo += t.f;
    t.u = u & 0xFFFF0000u; hi += t.f;
}
__device__ inline void bf2(unsigned u, float& lo, float& hi) {
    union { unsigned u; float f; } t;
    t.u = u << 16; lo = t.f;
    t.u = u & 0xFFFF0000u; hi = t.f;
}

// ---------------- utility: zero fill ----------------
__global__ void fill_zero(float* __restrict__ p, int n4) {
    float4* p4 = (float4*)p;
    for (int i = blockIdx.x * blockDim.x + threadIdx.x; i < n4; i += gridDim.x * blockDim.x)
        p4[i] = make_float4(0.f, 0.f, 0.f, 0.f);
}

// ---------------- fp32 -> bf16 convert ----------------
__global__ __launch_bounds__(256) void f32_to_bf16(const float* __restrict__ in,
                                                   u16* __restrict__ out, int n8) {
    const float4* in4 = (const float4*)in;
    uint4* out4 = (uint4*)out;
    for (int i = blockIdx.x * blockDim.x + threadIdx.x; i < n8; i += gridDim.x * blockDim.x) {
        float4 a = in4[2 * i], b = in4[2 * i + 1];
        uint4 u;
        u.x = pack2(a.x, a.y); u.y = pack2(a.z, a.w);
        u.z = pack2(b.x, b.y); u.w = pack2(b.z, b.w);
        out4[i] = u;
    }
}

// ---------------- CSR build ----------------
__global__ void deg_count(const int* __restrict__ dst, int* __restrict__ deg, int E) {
    int i = blockIdx.x * blockDim.x + threadIdx.x;
    if (i < E) atomicAdd(&deg[dst[i]], 1);
}

__global__ __launch_bounds__(256) void scan_phase1(const int* __restrict__ deg,
                                                   int* __restrict__ rowptr,
                                                   int* __restrict__ blocksum, int n) {
    __shared__ int s[256];
    const int t = threadIdx.x;
    const int i = blockIdx.x * 256 + t;
    int d = (i < n) ? deg[i] : 0;
    s[t] = d;
    __syncthreads();
    for (int off = 1; off < 256; off <<= 1) {
        int v = (t >= off) ? s[t - off] : 0;
        __syncthreads();
        s[t] += v;
        __syncthreads();
    }
    if (i < n) rowptr[i] = s[t] - d;
    if (t == 255) blocksum[blockIdx.x] = s[t];
}

__global__ __launch_bounds__(256) void scan_phase2(int* __restrict__ blocksum,
                                                   int* __restrict__ rowptr, int nb, int n) {
    __shared__ int s[256];
    const int t = threadIdx.x;
    int d = (t < nb) ? blocksum[t] : 0;
    s[t] = d;
    __syncthreads();
    for (int off = 1; off < 256; off <<= 1) {
        int v = (t >= off) ? s[t - off] : 0;
        __syncthreads();
        s[t] += v;
        __syncthreads();
    }
    if (t < nb) blocksum[t] = s[t] - d;
    if (t == 255) rowptr[n] = s[t];
}

__global__ __launch_bounds__(256) void scan_phase3(int* __restrict__ rowptr,
                                                   const int* __restrict__ blocksum,
                                                   const int* __restrict__ deg,
                                                   float* __restrict__ inv, int n) {
    int i = blockIdx.x * 256 + threadIdx.x;
    if (i >= n) return;
    rowptr[i] += blocksum[i >> 8];
    inv[i] = 1.0f / fmaxf((float)deg[i], 1.0f);
}

__global__ void csr_fill(const int* __restrict__ src, const int* __restrict__ dst,
                         const int* __restrict__ rowptr, int* __restrict__ cursor,
                         int* __restrict__ csr, int E) {
    int e = blockIdx.x * blockDim.x + threadIdx.x;
    if (e >= E) return;
    int d = dst[e];
    int p = atomicAdd(&cursor[d], 1);
    csr[rowptr[d] + p] = src[e];
}

// ---------------- gather-mean (layer 1: bf16 in, bf16 out, fp32 accumulate) ----------------
template <int KH>
__global__ __launch_bounds__(256) void gather_mean_bf16(const u16* __restrict__ F,
                                                        const int* __restrict__ rowptr,
                                                        const int* __restrict__ csr,
                                                        const float* __restrict__ inv,
                                                        u16* __restrict__ Sout, int N) {
    constexpr int CG = KH / 8;
    constexpr int NPB = 256 / CG;
    const int c = threadIdx.x % CG;
    const int node = blockIdx.x * NPB + threadIdx.x / CG;
    if (node >= N) return;
    const uint4* F4 = (const uint4*)F;
    float a0 = 0, a1 = 0, a2 = 0, a3 = 0, a4 = 0, a5 = 0, a6 = 0, a7 = 0;
    const int beg = rowptr[node], end = rowptr[node + 1];
    int k = beg;
    for (; k + 3 < end; k += 4) {
        uint4 v0 = F4[(size_t)csr[k] * CG + c];
        uint4 v1 = F4[(size_t)csr[k + 1] * CG + c];
        uint4 v2 = F4[(size_t)csr[k + 2] * CG + c];
        uint4 v3 = F4[(size_t)csr[k + 3] * CG + c];
        addbf2(v0.x, a0, a1); addbf2(v0.y, a2, a3); addbf2(v0.z, a4, a5); addbf2(v0.w, a6, a7);
        addbf2(v1.x, a0, a1); addbf2(v1.y, a2, a3); addbf2(v1.z, a4, a5); addbf2(v1.w, a6, a7);
        addbf2(v2.x, a0, a1); addbf2(v2.y, a2, a3); addbf2(v2.z, a4, a5); addbf2(v2.w, a6, a7);
        addbf2(v3.x, a0, a1); addbf2(v3.y, a2, a3); addbf2(v3.z, a4, a5); addbf2(v3.w, a6, a7);
    }
    for (; k < end; ++k) {
        uint4 v0 = F4[(size_t)csr[k] * CG + c];
        addbf2(v0.x, a0, a1); addbf2(v0.y, a2, a3); addbf2(v0.z, a4, a5); addbf2(v0.w, a6, a7);
    }
    const float w = inv[node];
    uint4 u;
    u.x = pack2(a0 * w, a1 * w); u.y = pack2(a2 * w, a3 * w);
    u.z = pack2(a4 * w, a5 * w); u.w = pack2(a6 * w, a7 * w);
    ((uint4*)Sout)[(size_t)node * CG + c] = u;
}

// ---------------- gather-add (layers 2,3): Hpre = mean-agg(P) + Q, PQ = [P|Q] rows ----------------
template <int D>
__global__ __launch_bounds__(256) void gather_add_bf16(const u16* __restrict__ PQ,
                                                       const int* __restrict__ rowptr,
                                                       const int* __restrict__ csr,
                                                       const float* __restrict__ inv,
                                                       u16* __restrict__ Hpre, int N) {
    constexpr int CG = D / 8;      // threads per node
    constexpr int NPB = 256 / CG;
    constexpr int RS4 = D / 4;     // uint4 per [P|Q] row
    const int c = threadIdx.x % CG;
    const int node = blockIdx.x * NPB + threadIdx.x / CG;
    if (node >= N) return;
    const uint4* PQ4 = (const uint4*)PQ;
    float a0 = 0, a1 = 0, a2 = 0, a3 = 0, a4 = 0, a5 = 0, a6 = 0, a7 = 0;
    const int beg = rowptr[node], end = rowptr[node + 1];
    int k = beg;
    for (; k + 3 < end; k += 4) {
        uint4 v0 = PQ4[(size_t)csr[k] * RS4 + c];
        uint4 v1 = PQ4[(size_t)csr[k + 1] * RS4 + c];
        uint4 v2 = PQ4[(size_t)csr[k + 2] * RS4 + c];
        uint4 v3 = PQ4[(size_t)csr[k + 3] * RS4 + c];
        addbf2(v0.x, a0, a1); addbf2(v0.y, a2, a3); addbf2(v0.z, a4, a5); addbf2(v0.w, a6, a7);
        addbf2(v1.x, a0, a1); addbf2(v1.y, a2, a3); addbf2(v1.z, a4, a5); addbf2(v1.w, a6, a7);
        addbf2(v2.x, a0, a1); addbf2(v2.y, a2, a3); addbf2(v2.z, a4, a5); addbf2(v2.w, a6, a7);
        addbf2(v3.x, a0, a1); addbf2(v3.y, a2, a3); addbf2(v3.z, a4, a5); addbf2(v3.w, a6, a7);
    }
    for (; k < end; ++k) {
        uint4 v0 = PQ4[(size_t)csr[k] * RS4 + c];
        addbf2(v0.x, a0, a1); addbf2(v0.y, a2, a3); addbf2(v0.z, a4, a5); addbf2(v0.w, a6, a7);
    }
    const float w = inv[node];
    uint4 q = PQ4[(size_t)node * RS4 + D / 8 + c];
    float q0, q1, q2, q3, q4, q5, q6, q7;
    bf2(q.x, q0, q1); bf2(q.y, q2, q3); bf2(q.z, q4, q5); bf2(q.w, q6, q7);
    uint4 u;
    u.x = pack2(a0 * w + q0, a1 * w + q1);
    u.y = pack2(a2 * w + q2, a3 * w + q3);
    u.z = pack2(a4 * w + q4, a5 * w + q5);
    u.w = pack2(a6 * w + q6, a7 * w + q7);
    ((uint4*)Hpre)[(size_t)node * (D / 8) + c] = u;
}

// ---------------- weight prep ----------------
template <int KH, int NOUT>
__global__ __launch_bounds__(256) void wt_build(const float* __restrict__ Wl,
                                                const float* __restrict__ Wr,
                                                u16* __restrict__ WT) {
    constexpr int K = 2 * KH;
    int idx = blockIdx.x * 256 + threadIdx.x;
    if (idx >= NOUT * K) return;
    int n = idx / K, k = idx % K;
    float v = (k < KH) ? Wl[(size_t)k * NOUT + n] : Wr[(size_t)(k - KH) * NOUT + n];
    WT[idx] = f2bf(v);
}

template <int K, int D>
__global__ __launch_bounds__(256) void wt_build_cat(const float* __restrict__ Wl,
                                                    const float* __restrict__ Wr,
                                                    u16* __restrict__ WT) {
    int idx = blockIdx.x * 256 + threadIdx.x;
    if (idx >= 2 * D * K) return;
    int n = idx / K, k = idx % K;
    float v = (n < D) ? Wl[(size_t)k * D + n] : Wr[(size_t)k * D + (n - D)];
    WT[idx] = f2bf(v);
}

__global__ void bias_cat(const float* __restrict__ b, float* __restrict__ out, int half) {
    int j = blockIdx.x * blockDim.x + threadIdx.x;
    if (j < half) out[j] = 0.f;
    else if (j < 2 * half) out[j] = b[j - half];
}

// ---------------- MFMA GEMM: H = A @ W + b (opt. [S|X] concat-K, opt. fused BN stats) ----------------
template <int KH, int K, int NOUT, bool STATS>
__global__ __launch_bounds__(256, 1) void sage_gemm(const u16* __restrict__ S,
                                                    const u16* __restrict__ X,
                                                    const u16* __restrict__ WT,
                                                    const float* __restrict__ BL,
                                                    u16* __restrict__ Hb,
                                                    float* __restrict__ sums,
                                                    float* __restrict__ sumsq, int M) {
    constexpr int NK = K / 32;
    constexpr int FN = NOUT / 32;
    constexpr int BUFSZ = 4096 + NOUT * 32;
    __shared__ __align__(16) u16 lds[2][BUFSZ];
    const int t = threadIdx.x;
    const int wid = t >> 6, lane = t & 63;
    const int row0 = blockIdx.x * 128;
    const int wm = wid >> 1, wn = wid & 1;
    const int fr = lane & 15, fc = lane >> 4;

    const int swz8 = (((lane & 3) ^ ((lane >> 3) & 3)) * 8);

    auto stage = [&](int buf, int ks) {
        const int k0 = ks * 32;
        const u16* srcA;
        int kb;
        if (k0 < KH) { srcA = S; kb = k0; } else { srcA = X; kb = k0 - KH; }
#pragma unroll
        for (int jj = 0; jj < 2; ++jj) {
            int j = wid + jj * 4;
            const u16* g = srcA + (size_t)(row0 + j * 16 + (lane >> 2)) * KH + kb + swz8;
            __builtin_amdgcn_global_load_lds(
                (const __attribute__((address_space(1))) void*)g,
                (__attribute__((address_space(3))) void*)&lds[buf][j * 512], 16, 0, 0);
        }
#pragma unroll
        for (int jj = 0; jj < NOUT / 64; ++jj) {
            int j = wid * (NOUT / 64) + jj;
            const u16* gb = WT + (size_t)(j * 16 + (lane >> 2)) * K + k0 + swz8;
            __builtin_amdgcn_global_load_lds(
                (const __attribute__((address_space(1))) void*)gb,
                (__attribute__((address_space(3))) void*)&lds[buf][4096 + j * 512], 16, 0, 0);
        }
    };

    f32x4 acc[4][FN] = {};

    stage(0, 0);
    for (int ks = 0; ks < NK; ++ks) {
        __syncthreads();
        if (ks + 1 < NK) stage((ks + 1) & 1, ks + 1);
        const u16* A = &lds[ks & 1][0];
        const u16* B = &lds[ks & 1][4096];
        const int swr = (fr >> 1) & 3;
        const int kc = (fc ^ swr) * 8;
        bf16x8 a[4], b[FN];
#pragma unroll
        for (int fm = 0; fm < 4; ++fm)
            a[fm] = *(const bf16x8*)&A[(wm * 64 + fm * 16 + fr) * 32 + kc];
#pragma unroll
        for (int fn = 0; fn < FN; ++fn)
            b[fn] = *(const bf16x8*)&B[(wn * (NOUT / 2) + fn * 16 + fr) * 32 + kc];
#pragma unroll
        for (int fm = 0; fm < 4; ++fm)
#pragma unroll
            for (int fn = 0; fn < FN; ++fn)
                acc[fm][fn] = __builtin_amdgcn_mfma_f32_16x16x32_bf16(a[fm], b[fn], acc[fm][fn], 0, 0, 0);
    }

    const int cw = wn * (NOUT / 2);
    float bias[FN], s[FN], ss[FN];
#pragma unroll
    for (int fn = 0; fn < FN; ++fn) {
        bias[fn] = BL[cw + fn * 16 + fr];
        s[fn] = 0.f; ss[fn] = 0.f;
    }
#pragma unroll
    for (int fm = 0; fm < 4; ++fm) {
#pragma unroll
        for (int q = 0; q < 4; ++q) {
            int r = row0 + wm * 64 + fm * 16 + fc * 4 + q;
            if (r < M) {
#pragma unroll
                for (int fn = 0; fn < FN; ++fn) {
                    float h = acc[fm][fn][q] + bias[fn];
                    Hb[(size_t)r * NOUT + cw + fn * 16 + fr] = f2bf(h);
                    if constexpr (STATS) { s[fn] += h; ss[fn] += h * h; }
                }
            }
        }
    }
    if constexpr (STATS) {
#pragma unroll
        for (int fn = 0; fn < FN; ++fn) {
            float sv = s[fn], sq = ss[fn];
            sv += __shfl_xor(sv, 16); sv += __shfl_xor(sv, 32);
            sq += __shfl_xor(sq, 16); sq += __shfl_xor(sq, 32);
            if (fc == 0) {
                atomicAdd(&sums[cw + fn * 16 + fr], sv);
                atomicAdd(&sumsq[cw + fn * 16 + fr], sq);
            }
        }
    }
}

// ---------------- BN column stats (bf16 input, vectorized, two-level reduce) ----------------
template <int M>
__global__ __launch_bounds__(256) void col_stats_fast(const u16* __restrict__ H,
                                                      float* __restrict__ sums,
                                                      float* __restrict__ sumsq, int nrows) {
    constexpr int C4 = M / 8;        // uint4 chunks per row
    constexpr int RPB = 256 / C4;    // rows per block-pass
    __shared__ float ls[M], lss[M];
    for (int j = threadIdx.x; j < M; j += 256) { ls[j] = 0.f; lss[j] = 0.f; }
    __syncthreads();
    const int c = threadIdx.x % C4;
    const int rg = threadIdx.x / C4;
    float s[8] = {}, ss[8] = {};
    const uint4* H4 = (const uint4*)H;
    for (int r = blockIdx.x * RPB + rg; r < nrows; r += gridDim.x * RPB) {
        uint4 v = H4[(size_t)r * C4 + c];
        float x0, x1, x2, x3, x4, x5, x6, x7;
        bf2(v.x, x0, x1); bf2(v.y, x2, x3); bf2(v.z, x4, x5); bf2(v.w, x6, x7);
        s[0] += x0; ss[0] += x0 * x0;  s[1] += x1; ss[1] += x1 * x1;
        s[2] += x2; ss[2] += x2 * x2;  s[3] += x3; ss[3] += x3 * x3;
        s[4] += x4; ss[4] += x4 * x4;  s[5] += x5; ss[5] += x5 * x5;
        s[6] += x6; ss[6] += x6 * x6;  s[7] += x7; ss[7] += x7 * x7;
    }
#pragma unroll
    for (int j = 0; j < 8; ++j) {
        atomicAdd(&ls[c * 8 + j], s[j]);
        atomicAdd(&lss[c * 8 + j], ss[j]);
    }
    __syncthreads();
    for (int j = threadIdx.x; j < M; j += 256) {
        atomicAdd(&sums[j], ls[j]);
        atomicAdd(&sumsq[j], lss[j]);
    }
}

// ---------------- BN finalize ----------------
template <int M>
__global__ void bn_finalize(const float* __restrict__ sums, const float* __restrict__ sumsq,
                            const float* __restrict__ g, const float* __restrict__ beta,
                            float* __restrict__ scale, float* __restrict__ shift, int nrows) {
    int j = threadIdx.x;
    if (j >= M) return;
    float mean = sums[j] / nrows;
    float var = fmaxf(sumsq[j] / nrows - mean * mean, 0.f);
    float sc = g[j] * rsqrtf(var + BN_EPS);
    scale[j] = sc;
    shift[j] = beta[j] - mean * sc;
}

// ---------------- BN apply + ReLU (bf16 -> bf16) ----------------
template <int M>
__global__ __launch_bounds__(256) void bn_relu_bf16(const u16* __restrict__ Hb,
                                                    const float* __restrict__ scale,
                                                    const float* __restrict__ shift,
                                                    u16* __restrict__ Ob, int n8) {
    const uint4* H4 = (const uint4*)Hb;
    uint4* O4 = (uint4*)Ob;
    const float4* sc4 = (const float4*)scale;
    const float4* sh4 = (const float4*)shift;
    for (int i = blockIdx.x * blockDim.x + threadIdx.x; i < n8; i += gridDim.x * blockDim.x) {
        int jg = i % (M / 8);
        uint4 v = H4[i];
        float4 s0 = sc4[jg * 2], s1 = sc4[jg * 2 + 1];
        float4 b0 = sh4[jg * 2], b1 = sh4[jg * 2 + 1];
        float x0, x1, x2, x3, x4, x5, x6, x7;
        bf2(v.x, x0, x1); bf2(v.y, x2, x3); bf2(v.z, x4, x5); bf2(v.w, x6, x7);
        x0 = fmaxf(fmaf(x0, s0.x, b0.x), 0.f);
        x1 = fmaxf(fmaf(x1, s0.y, b0.y), 0.f);
        x2 = fmaxf(fmaf(x2, s0.z, b0.z), 0.f);
        x3 = fmaxf(fmaf(x3, s0.w, b0.w), 0.f);
        x4 = fmaxf(fmaf(x4, s1.x, b1.x), 0.f);
        x5 = fmaxf(fmaf(x5, s1.y, b1.y), 0.f);
        x6 = fmaxf(fmaf(x6, s1.z, b1.z), 0.f);
        x7 = fmaxf(fmaf(x7, s1.w, b1.w), 0.f);
        uint4 u;
        u.x = pack2(x0, x1); u.y = pack2(x2, x3);
        u.z = pack2(x4, x5); u.w = pack2(x6, x7);
        O4[i] = u;
    }
}

// ---------------- head: out = H3 @ wh + bh ----------------
__global__ __launch_bounds__(256) void head_bf16_v2(const u16* __restrict__ H3,
                                                    const float* __restrict__ wh,
                                                    const float* __restrict__ bh,
                                                    float* __restrict__ out, int n) {
    int i = blockIdx.x * blockDim.x + threadIdx.x;
    if (i >= n) return;
    const uint4* h4 = (const uint4*)(H3 + (size_t)i * 64);
    float acc = bh[0];
#pragma unroll
    for (int c = 0; c < 8; ++c) {
        uint4 v = h4[c];
        float x0, x1, x2, x3, x4, x5, x6, x7;
        bf2(v.x, x0, x1); bf2(v.y, x2, x3); bf2(v.z, x4, x5); bf2(v.w, x6, x7);
        const float* w = wh + c * 8;
        acc += x0 * w[0] + x1 * w[1] + x2 * w[2] + x3 * w[3] +
               x4 * w[4] + x5 * w[5] + x6 * w[6] + x7 * w[7];
    }
    out[i] = acc;
}

// ---------------- launch ----------------
extern "C" void kernel_launch(void* const* d_in, const int* in_sizes, int n_in,
                              void* d_out, int out_size, void* d_ws, size_t ws_size,
                              hipStream_t stream) {
    const int N = N_NODES, E = N_EDGES;
    const float* x   = (const float*)d_in[0];
    const int*   ei  = (const int*)d_in[1];
    const int*   src = ei;
    const int*   dst = ei + E;
    const float* w1l = (const float*)d_in[2];
    const float* b1l = (const float*)d_in[3];
    const float* w1r = (const float*)d_in[4];
    const float* g1  = (const float*)d_in[5];
    const float* be1 = (const float*)d_in[6];
    const float* w2l = (const float*)d_in[7];
    const float* b2l = (const float*)d_in[8];
    const float* w2r = (const float*)d_in[9];
    const float* g2  = (const float*)d_in[10];
    const float* be2 = (const float*)d_in[11];
    const float* w3l = (const float*)d_in[12];
    const float* b3l = (const float*)d_in[13];
    const float* w3r = (const float*)d_in[14];
    const float* g3  = (const float*)d_in[15];
    const float* be3 = (const float*)d_in[16];
    const float* wh  = (const float*)d_in[17];
    const float* bh  = (const float*)d_in[18];
    float* out = (float*)d_out;

    // ---- workspace layout (256B-aligned regions) ----
    char* base = (char*)d_ws;
    size_t off = 0;
    auto alloc = [&](size_t bytes) -> void* {
        void* r = base + off;
        off += (bytes + 255) & ~(size_t)255;
        return r;
    };
    const int NB = (N + 255) / 256;  // 196 scan blocks
    int*   rowptr = (int*)alloc((N + 8) * sizeof(int));
    int*   csr    = (int*)alloc((size_t)E * sizeof(int));
    int*   ints2  = (int*)alloc(2 * (size_t)N * sizeof(int));  // deg_i | cursor
    int*   deg_i  = ints2;
    int*   cursor = ints2 + N;
    int*   bsum   = (int*)alloc(256 * sizeof(int));
    float* inv    = (float*)alloc(N * sizeof(float));
    u16*   xb     = (u16*)alloc((size_t)NP * 256 * 2);
    u16*   sB     = (u16*)alloc((size_t)NP * 256 * 2);
    u16*   h1b    = (u16*)alloc((size_t)NP * 256 * 2);
    u16*   h2b    = (u16*)alloc((size_t)NP * 128 * 2);
    u16*   h3b    = (u16*)alloc((size_t)NP * 64 * 2);
    u16*   hpre   = (u16*)alloc((size_t)NP * 256 * 2);   // layer1 pre-BN; layers 2/3 [P|Q]
    u16*   h2pre  = (u16*)alloc((size_t)NP * 128 * 2);
    u16*   h3pre  = (u16*)alloc((size_t)NP * 64 * 2);
    u16*   wt     = (u16*)alloc((size_t)256 * 512 * 2);
    float* stats  = (float*)alloc(1024 * sizeof(float));
    float* bias2  = (float*)alloc(256 * sizeof(float));
    float* bias3  = (float*)alloc(128 * sizeof(float));
    float* sums = stats, *sumsq = stats + 256, *scale = stats + 512, *shift = stats + 768;

    auto zero = [&](void* p, size_t nfloats) {
        int n4 = (int)(nfloats / 4);
        int blocks = (n4 + 255) / 256;
        if (blocks > 2048) blocks = 2048;
        fill_zero<<<blocks, 256, 0, stream>>>((float*)p, n4);
    };

    // ---- prep: x -> bf16 ----
    f32_to_bf16<<<2048, 256, 0, stream>>>(x, xb, N * 256 / 8);

    // ---- CSR build (3-phase parallel scan) ----
    zero(ints2, 2 * (size_t)N);
    deg_count<<<(E + 255) / 256, 256, 0, stream>>>(dst, deg_i, E);
    scan_phase1<<<NB, 256, 0, stream>>>(deg_i, rowptr, bsum, N);
    scan_phase2<<<1, 256, 0, stream>>>(bsum, rowptr, NB, N);
    scan_phase3<<<NB, 256, 0, stream>>>(rowptr, bsum, deg_i, inv, N);
    csr_fill<<<(E + 255) / 256, 256, 0, stream>>>(src, dst, rowptr, cursor, csr, E);

    const int MB = NP / 128;  // 391

    // ---- layer 1: agg-first (256 -> 256), fused [S|X] GEMM K=512, stats in epilogue ----
    gather_mean_bf16<256><<<(N * 32 + 255) / 256, 256, 0, stream>>>(xb, rowptr, csr, inv, sB, N);
    wt_build<256, 256><<<(256 * 512 + 255) / 256, 256, 0, stream>>>(w1l, w1r, wt);
    zero(sums, 512);
    sage_gemm<256, 512, 256, true><<<MB, 256, 0, stream>>>(sB, xb, wt, b1l, hpre, sums, sumsq, N);
    bn_finalize<256><<<1, 256, 0, stream>>>(sums, sumsq, g1, be1, scale, shift, N);
    bn_relu_bf16<256><<<2048, 256, 0, stream>>>(hpre, scale, shift, h1b, N * 256 / 8);

    // ---- layer 2: transform-first (256 -> 128) ----
    wt_build_cat<256, 128><<<(256 * 256 + 255) / 256, 256, 0, stream>>>(w2l, w2r, wt);
    bias_cat<<<1, 256, 0, stream>>>(b2l, bias2, 128);
    sage_gemm<256, 256, 256, false><<<MB, 256, 0, stream>>>(h1b, h1b, wt, bias2, hpre, nullptr, nullptr, N);
    gather_add_bf16<128><<<(N * 16 + 255) / 256, 256, 0, stream>>>(hpre, rowptr, csr, inv, h2pre, N);
    zero(sums, 512);
    col_stats_fast<128><<<256, 256, 0, stream>>>(h2pre, sums, sumsq, N);
    bn_finalize<128><<<1, 128, 0, stream>>>(sums, sumsq, g2, be2, scale, shift, N);
    bn_relu_bf16<128><<<2048, 256, 0, stream>>>(h2pre, scale, shift, h2b, N * 128 / 8);

    // ---- layer 3: transform-first (128 -> 64) ----
    wt_build_cat<128, 64><<<(128 * 128 + 255) / 256, 256, 0, stream>>>(w3l, w3r, wt);
    bias_cat<<<1, 128, 0, stream>>>(b3l, bias3, 64);
    sage_gemm<128, 128, 128, false><<<MB, 256, 0, stream>>>(h2b, h2b, wt, bias3, hpre, nullptr, nullptr, N);
    gather_add_bf16<64><<<(N * 8 + 255) / 256, 256, 0, stream>>>(hpre, rowptr, csr, inv, h3pre, N);
    zero(sums, 512);
    col_stats_fast<64><<<256, 256, 0, stream>>>(h3pre, sums, sumsq, N);
    bn_finalize<64><<<1, 64, 0, stream>>>(sums, sumsq, g3, be3, scale, shift, N);
    bn_relu_bf16<64><<<2048, 256, 0, stream>>>(h3pre, scale, shift, h3b, N * 64 / 8);

    // ---- head ----
    head_bf16_v2<<<(N + 255) / 256, 256, 0, stream>>>(h3b, wh, bh, out, N);
}

// Round 8
// 319.751 us; speedup vs baseline: 1.2353x; 1.0442x over previous
//
#include <hip/hip_runtime.h>
#include <cstddef>
#include <cstdint>

#define N_NODES 50000
#define N_EDGES 800000
#define NP 50048   // 391 * 128, padded row count
static constexpr float BN_EPS = 1e-5f;

typedef unsigned short u16;
typedef short bf16x8 __attribute__((ext_vector_type(8)));
typedef float f32x4 __attribute__((ext_vector_type(4)));

// ---------------- helpers ----------------
__device__ inline u16 f2bf(float f) {
    union { float f; unsigned u; } v; v.f = f;
    unsigned r = v.u + 0x7fffu + ((v.u >> 16) & 1u);
    return (u16)(r >> 16);
}
__device__ inline unsigned pack2(float a, float b) {
    return (unsigned)f2bf(a) | ((unsigned)f2bf(b) << 16);
}
__device__ inline void addbf2(unsigned u, float& lo, float& hi) {
    union { unsigned u; float f; } t;
    t.u = u << 16; lo += t.f;
    t.u = u & 0xFFFF0000u; hi += t.f;
}
__device__ inline void bf2(unsigned u, float& lo, float& hi) {
    union { unsigned u; float f; } t;
    t.u = u << 16; lo = t.f;
    t.u = u & 0xFFFF0000u; hi = t.f;
}
__device__ inline uint4 bnrelu_pack(uint4 v, float4 sc0, float4 sc1, float4 sh0, float4 sh1) {
    float x0, x1, x2, x3, x4, x5, x6, x7;
    bf2(v.x, x0, x1); bf2(v.y, x2, x3); bf2(v.z, x4, x5); bf2(v.w, x6, x7);
    x0 = fmaxf(fmaf(x0, sc0.x, sh0.x), 0.f); x1 = fmaxf(fmaf(x1, sc0.y, sh0.y), 0.f);
    x2 = fmaxf(fmaf(x2, sc0.z, sh0.z), 0.f); x3 = fmaxf(fmaf(x3, sc0.w, sh0.w), 0.f);
    x4 = fmaxf(fmaf(x4, sc1.x, sh1.x), 0.f); x5 = fmaxf(fmaf(x5, sc1.y, sh1.y), 0.f);
    x6 = fmaxf(fmaf(x6, sc1.z, sh1.z), 0.f); x7 = fmaxf(fmaf(x7, sc1.w, sh1.w), 0.f);
    uint4 u;
    u.x = pack2(x0, x1); u.y = pack2(x2, x3);
    u.z = pack2(x4, x5); u.w = pack2(x6, x7);
    return u;
}

// ---------------- fp32 -> bf16 convert + deg zero (fused) ----------------
__global__ __launch_bounds__(256) void f32_to_bf16_zero(const float* __restrict__ in,
                                                        u16* __restrict__ out, int n8,
                                                        int* __restrict__ dz, int ndz4) {
    int4* d4 = (int4*)dz;
    for (int i = blockIdx.x * 256 + threadIdx.x; i < ndz4; i += gridDim.x * 256)
        d4[i] = make_int4(0, 0, 0, 0);
    const float4* in4 = (const float4*)in;
    uint4* out4 = (uint4*)out;
    for (int i = blockIdx.x * 256 + threadIdx.x; i < n8; i += gridDim.x * 256) {
        float4 a = in4[2 * i], b = in4[2 * i + 1];
        uint4 u;
        u.x = pack2(a.x, a.y); u.y = pack2(a.z, a.w);
        u.z = pack2(b.x, b.y); u.w = pack2(b.z, b.w);
        out4[i] = u;
    }
}

// ---------------- CSR build ----------------
__global__ void deg_count(const int* __restrict__ dst, int* __restrict__ deg, int E) {
    int i = blockIdx.x * blockDim.x + threadIdx.x;
    if (i < E) atomicAdd(&deg[dst[i]], 1);
}

__global__ __launch_bounds__(256) void scan_phase1(const int* __restrict__ deg,
                                                   int* __restrict__ rowptr,
                                                   int* __restrict__ blocksum, int n) {
    __shared__ int s[256];
    const int t = threadIdx.x;
    const int i = blockIdx.x * 256 + t;
    int d = (i < n) ? deg[i] : 0;
    s[t] = d;
    __syncthreads();
    for (int off = 1; off < 256; off <<= 1) {
        int v = (t >= off) ? s[t - off] : 0;
        __syncthreads();
        s[t] += v;
        __syncthreads();
    }
    if (i < n) rowptr[i] = s[t] - d;
    if (t == 255) blocksum[blockIdx.x] = s[t];
}

// also zeroes the stats block (sums/sumsq for 3 layers)
__global__ __launch_bounds__(256) void scan_phase2(int* __restrict__ blocksum,
                                                   int* __restrict__ rowptr,
                                                   float* __restrict__ statszero, int nstats,
                                                   int nb, int n) {
    for (int j = threadIdx.x; j < nstats; j += 256) statszero[j] = 0.f;
    __shared__ int s[256];
    const int t = threadIdx.x;
    int d = (t < nb) ? blocksum[t] : 0;
    s[t] = d;
    __syncthreads();
    for (int off = 1; off < 256; off <<= 1) {
        int v = (t >= off) ? s[t - off] : 0;
        __syncthreads();
        s[t] += v;
        __syncthreads();
    }
    if (t < nb) blocksum[t] = s[t] - d;
    if (t == 255) rowptr[n] = s[t];
}

// also zeroes cursor
__global__ __launch_bounds__(256) void scan_phase3(int* __restrict__ rowptr,
                                                   const int* __restrict__ blocksum,
                                                   const int* __restrict__ deg,
                                                   float* __restrict__ inv,
                                                   int* __restrict__ cursor, int n) {
    int i = blockIdx.x * 256 + threadIdx.x;
    if (i >= n) return;
    rowptr[i] += blocksum[i >> 8];
    inv[i] = 1.0f / fmaxf((float)deg[i], 1.0f);
    cursor[i] = 0;
}

__global__ void csr_fill(const int* __restrict__ src, const int* __restrict__ dst,
                         const int* __restrict__ rowptr, int* __restrict__ cursor,
                         int* __restrict__ csr, int E) {
    int e = blockIdx.x * blockDim.x + threadIdx.x;
    if (e >= E) return;
    int d = dst[e];
    int p = atomicAdd(&cursor[d], 1);
    csr[rowptr[d] + p] = src[e];
}

// ---------------- weight/bias prep (all layers, one dispatch) ----------------
__global__ __launch_bounds__(256) void prep_weights(const float* __restrict__ w1l, const float* __restrict__ w1r,
                                                    const float* __restrict__ w2l, const float* __restrict__ w2r,
                                                    const float* __restrict__ w3l, const float* __restrict__ w3r,
                                                    const float* __restrict__ b2l, const float* __restrict__ b3l,
                                                    u16* __restrict__ wt1, u16* __restrict__ wt2,
                                                    u16* __restrict__ wt3,
                                                    float* __restrict__ bias2, float* __restrict__ bias3) {
    int idx = blockIdx.x * 256 + threadIdx.x;
    if (idx < 131072) {  // wt1[n][k]: n<256, K=512 concat-K: k<256 -> w1l[k][n], else w1r[k-256][n]
        int n = idx >> 9, k = idx & 511;
        float v = (k < 256) ? w1l[(size_t)k * 256 + n] : w1r[(size_t)(k - 256) * 256 + n];
        wt1[idx] = f2bf(v); return;
    }
    idx -= 131072;
    if (idx < 65536) {   // wt2[n][k]: n<256 (concat-N, D=128), K=256
        int n = idx >> 8, k = idx & 255;
        float v = (n < 128) ? w2l[(size_t)k * 128 + n] : w2r[(size_t)k * 128 + (n - 128)];
        wt2[idx] = f2bf(v); return;
    }
    idx -= 65536;
    if (idx < 16384) {   // wt3[n][k]: n<128 (concat-N, D=64), K=128
        int n = idx >> 7, k = idx & 127;
        float v = (n < 64) ? w3l[(size_t)k * 64 + n] : w3r[(size_t)k * 64 + (n - 64)];
        wt3[idx] = f2bf(v); return;
    }
    idx -= 16384;
    if (idx < 256) { bias2[idx] = (idx < 128) ? 0.f : b2l[idx - 128]; return; }
    idx -= 256;
    if (idx < 128) { bias3[idx] = (idx < 64) ? 0.f : b3l[idx - 64]; return; }
}

// ---------------- gather-mean (layer 1) ----------------
template <int KH>
__global__ __launch_bounds__(256) void gather_mean_bf16(const u16* __restrict__ F,
                                                        const int* __restrict__ rowptr,
                                                        const int* __restrict__ csr,
                                                        const float* __restrict__ inv,
                                                        u16* __restrict__ Sout, int N) {
    constexpr int CG = KH / 8;
    constexpr int NPB = 256 / CG;
    const int c = threadIdx.x % CG;
    const int node = blockIdx.x * NPB + threadIdx.x / CG;
    if (node >= N) return;
    const uint4* F4 = (const uint4*)F;
    float a0 = 0, a1 = 0, a2 = 0, a3 = 0, a4 = 0, a5 = 0, a6 = 0, a7 = 0;
    const int beg = rowptr[node], end = rowptr[node + 1];
    int k = beg;
    for (; k + 7 < end; k += 8) {
        uint4 v0 = F4[(size_t)csr[k] * CG + c];
        uint4 v1 = F4[(size_t)csr[k + 1] * CG + c];
        uint4 v2 = F4[(size_t)csr[k + 2] * CG + c];
        uint4 v3 = F4[(size_t)csr[k + 3] * CG + c];
        uint4 v4 = F4[(size_t)csr[k + 4] * CG + c];
        uint4 v5 = F4[(size_t)csr[k + 5] * CG + c];
        uint4 v6 = F4[(size_t)csr[k + 6] * CG + c];
        uint4 v7 = F4[(size_t)csr[k + 7] * CG + c];
        addbf2(v0.x, a0, a1); addbf2(v0.y, a2, a3); addbf2(v0.z, a4, a5); addbf2(v0.w, a6, a7);
        addbf2(v1.x, a0, a1); addbf2(v1.y, a2, a3); addbf2(v1.z, a4, a5); addbf2(v1.w, a6, a7);
        addbf2(v2.x, a0, a1); addbf2(v2.y, a2, a3); addbf2(v2.z, a4, a5); addbf2(v2.w, a6, a7);
        addbf2(v3.x, a0, a1); addbf2(v3.y, a2, a3); addbf2(v3.z, a4, a5); addbf2(v3.w, a6, a7);
        addbf2(v4.x, a0, a1); addbf2(v4.y, a2, a3); addbf2(v4.z, a4, a5); addbf2(v4.w, a6, a7);
        addbf2(v5.x, a0, a1); addbf2(v5.y, a2, a3); addbf2(v5.z, a4, a5); addbf2(v5.w, a6, a7);
        addbf2(v6.x, a0, a1); addbf2(v6.y, a2, a3); addbf2(v6.z, a4, a5); addbf2(v6.w, a6, a7);
        addbf2(v7.x, a0, a1); addbf2(v7.y, a2, a3); addbf2(v7.z, a4, a5); addbf2(v7.w, a6, a7);
    }
    for (; k < end; ++k) {
        uint4 v0 = F4[(size_t)csr[k] * CG + c];
        addbf2(v0.x, a0, a1); addbf2(v0.y, a2, a3); addbf2(v0.z, a4, a5); addbf2(v0.w, a6, a7);
    }
    const float w = inv[node];
    uint4 u;
    u.x = pack2(a0 * w, a1 * w); u.y = pack2(a2 * w, a3 * w);
    u.z = pack2(a4 * w, a5 * w); u.w = pack2(a6 * w, a7 * w);
    ((uint4*)Sout)[(size_t)node * CG + c] = u;
}

// ---------------- gather-add (layers 2,3): Hpre = mean-agg(P) + Q ----------------
template <int D>
__global__ __launch_bounds__(256) void gather_add_bf16(const u16* __restrict__ PQ,
                                                       const int* __restrict__ rowptr,
                                                       const int* __restrict__ csr,
                                                       const float* __restrict__ inv,
                                                       u16* __restrict__ Hpre, int N) {
    constexpr int CG = D / 8;
    constexpr int NPB = 256 / CG;
    constexpr int RS4 = D / 4;
    const int c = threadIdx.x % CG;
    const int node = blockIdx.x * NPB + threadIdx.x / CG;
    if (node >= N) return;
    const uint4* PQ4 = (const uint4*)PQ;
    float a0 = 0, a1 = 0, a2 = 0, a3 = 0, a4 = 0, a5 = 0, a6 = 0, a7 = 0;
    const int beg = rowptr[node], end = rowptr[node + 1];
    int k = beg;
    for (; k + 3 < end; k += 4) {
        uint4 v0 = PQ4[(size_t)csr[k] * RS4 + c];
        uint4 v1 = PQ4[(size_t)csr[k + 1] * RS4 + c];
        uint4 v2 = PQ4[(size_t)csr[k + 2] * RS4 + c];
        uint4 v3 = PQ4[(size_t)csr[k + 3] * RS4 + c];
        addbf2(v0.x, a0, a1); addbf2(v0.y, a2, a3); addbf2(v0.z, a4, a5); addbf2(v0.w, a6, a7);
        addbf2(v1.x, a0, a1); addbf2(v1.y, a2, a3); addbf2(v1.z, a4, a5); addbf2(v1.w, a6, a7);
        addbf2(v2.x, a0, a1); addbf2(v2.y, a2, a3); addbf2(v2.z, a4, a5); addbf2(v2.w, a6, a7);
        addbf2(v3.x, a0, a1); addbf2(v3.y, a2, a3); addbf2(v3.z, a4, a5); addbf2(v3.w, a6, a7);
    }
    for (; k < end; ++k) {
        uint4 v0 = PQ4[(size_t)csr[k] * RS4 + c];
        addbf2(v0.x, a0, a1); addbf2(v0.y, a2, a3); addbf2(v0.z, a4, a5); addbf2(v0.w, a6, a7);
    }
    const float w = inv[node];
    uint4 q = PQ4[(size_t)node * RS4 + D / 8 + c];
    float q0, q1, q2, q3, q4, q5, q6, q7;
    bf2(q.x, q0, q1); bf2(q.y, q2, q3); bf2(q.z, q4, q5); bf2(q.w, q6, q7);
    uint4 u;
    u.x = pack2(a0 * w + q0, a1 * w + q1);
    u.y = pack2(a2 * w + q2, a3 * w + q3);
    u.z = pack2(a4 * w + q4, a5 * w + q5);
    u.w = pack2(a6 * w + q6, a7 * w + q7);
    ((uint4*)Hpre)[(size_t)node * (D / 8) + c] = u;
}

// ---------------- MFMA GEMM ----------------
// BNA=false: A staged via global_load_lds from S/X (concat-K). BNA=true: A reg-staged
// from S with fused y=relu(a*SC[k]+SH[k]) before swizzled ds_write (KH must equal K).
template <int KH, int K, int NOUT, bool STATS, bool BNA>
__global__ __launch_bounds__(256, 1) void sage_gemm(const u16* __restrict__ S,
                                                    const u16* __restrict__ X,
                                                    const u16* __restrict__ WT,
                                                    const float* __restrict__ BL,
                                                    const float* __restrict__ SC,
                                                    const float* __restrict__ SH,
                                                    u16* __restrict__ Hb,
                                                    float* __restrict__ sums,
                                                    float* __restrict__ sumsq, int M) {
    constexpr int NK = K / 32;
    constexpr int FN = NOUT / 32;
    constexpr int BUFSZ = 4096 + NOUT * 32;
    __shared__ __align__(16) u16 lds[2][BUFSZ];
    const int t = threadIdx.x;
    const int wid = t >> 6, lane = t & 63;
    const int row0 = blockIdx.x * 128;
    const int wm = wid >> 1, wn = wid & 1;
    const int fr = lane & 15, fc = lane >> 4;
    const int swz8 = (((lane & 3) ^ ((lane >> 3) & 3)) * 8);

    auto stageA_lds = [&](int buf, int ks) {
        const int k0 = ks * 32;
        const u16* srcA;
        int kb;
        if (k0 < KH) { srcA = S; kb = k0; } else { srcA = X; kb = k0 - KH; }
#pragma unroll
        for (int jj = 0; jj < 2; ++jj) {
            int j = wid + jj * 4;
            const u16* g = srcA + (size_t)(row0 + j * 16 + (lane >> 2)) * KH + kb + swz8;
            __builtin_amdgcn_global_load_lds(
                (const __attribute__((address_space(1))) void*)g,
                (__attribute__((address_space(3))) void*)&lds[buf][j * 512], 16, 0, 0);
        }
    };
    auto stageB = [&](int buf, int ks) {
        const int k0 = ks * 32;
#pragma unroll
        for (int jj = 0; jj < NOUT / 64; ++jj) {
            int j = wid * (NOUT / 64) + jj;
            const u16* gb = WT + (size_t)(j * 16 + (lane >> 2)) * K + k0 + swz8;
            __builtin_amdgcn_global_load_lds(
                (const __attribute__((address_space(1))) void*)gb,
                (__attribute__((address_space(3))) void*)&lds[buf][4096 + j * 512], 16, 0, 0);
        }
    };

    uint4 rA[2];
    auto loadA = [&](int ks) {
        const int k0 = ks * 32;
#pragma unroll
        for (int jj = 0; jj < 2; ++jj) {
            int j = wid + jj * 4;
            rA[jj] = *(const uint4*)(S + (size_t)(row0 + j * 16 + (lane >> 2)) * KH + k0 + swz8);
        }
    };
    auto writeA = [&](int buf, int ks) {
        const int k0 = ks * 32;
        float4 sc0 = *(const float4*)&SC[k0 + swz8];
        float4 sc1 = *(const float4*)&SC[k0 + swz8 + 4];
        float4 sh0 = *(const float4*)&SH[k0 + swz8];
        float4 sh1 = *(const float4*)&SH[k0 + swz8 + 4];
#pragma unroll
        for (int jj = 0; jj < 2; ++jj) {
            int j = wid + jj * 4;
            *(uint4*)&lds[buf][(size_t)j * 512 + lane * 8] = bnrelu_pack(rA[jj], sc0, sc1, sh0, sh1);
        }
    };

    f32x4 acc[4][FN] = {};

    auto compute = [&](int buf) {
        const u16* A = &lds[buf][0];
        const u16* B = &lds[buf][4096];
        const int swr = (fr >> 1) & 3;
        const int kc = (fc ^ swr) * 8;
        bf16x8 a[4], b[FN];
#pragma unroll
        for (int fm = 0; fm < 4; ++fm)
            a[fm] = *(const bf16x8*)&A[(wm * 64 + fm * 16 + fr) * 32 + kc];
#pragma unroll
        for (int fn = 0; fn < FN; ++fn)
            b[fn] = *(const bf16x8*)&B[(wn * (NOUT / 2) + fn * 16 + fr) * 32 + kc];
#pragma unroll
        for (int fm = 0; fm < 4; ++fm)
#pragma unroll
            for (int fn = 0; fn < FN; ++fn)
                acc[fm][fn] = __builtin_amdgcn_mfma_f32_16x16x32_bf16(a[fm], b[fn], acc[fm][fn], 0, 0, 0);
    };

    if constexpr (BNA) {
        static_assert(KH == K, "BNA requires single operand");
        loadA(0);
        writeA(0, 0);
        stageB(0, 0);
        if (NK > 1) loadA(1);
        for (int ks = 0; ks < NK; ++ks) {
            __syncthreads();
            if (ks + 1 < NK) {
                writeA((ks + 1) & 1, ks + 1);
                stageB((ks + 1) & 1, ks + 1);
                if (ks + 2 < NK) loadA(ks + 2);
            }
            compute(ks & 1);
        }
    } else {
        stageA_lds(0, 0);
        stageB(0, 0);
        for (int ks = 0; ks < NK; ++ks) {
            __syncthreads();
            if (ks + 1 < NK) {
                stageA_lds((ks + 1) & 1, ks + 1);
                stageB((ks + 1) & 1, ks + 1);
            }
            compute(ks & 1);
        }
    }

    // epilogue
    const int cw = wn * (NOUT / 2);
    float bias[FN], s[FN], ss[FN];
#pragma unroll
    for (int fn = 0; fn < FN; ++fn) {
        bias[fn] = BL[cw + fn * 16 + fr];
        s[fn] = 0.f; ss[fn] = 0.f;
    }
#pragma unroll
    for (int fm = 0; fm < 4; ++fm) {
#pragma unroll
        for (int q = 0; q < 4; ++q) {
            int r = row0 + wm * 64 + fm * 16 + fc * 4 + q;
            if (r < M) {
#pragma unroll
                for (int fn = 0; fn < FN; ++fn) {
                    float h = acc[fm][fn][q] + bias[fn];
                    Hb[(size_t)r * NOUT + cw + fn * 16 + fr] = f2bf(h);
                    if constexpr (STATS) { s[fn] += h; ss[fn] += h * h; }
                }
            }
        }
    }
    if constexpr (STATS) {
#pragma unroll
        for (int fn = 0; fn < FN; ++fn) {
            float sv = s[fn], sq = ss[fn];
            sv += __shfl_xor(sv, 16); sv += __shfl_xor(sv, 32);
            sq += __shfl_xor(sq, 16); sq += __shfl_xor(sq, 32);
            if (fc == 0) {
                atomicAdd(&sums[cw + fn * 16 + fr], sv);
                atomicAdd(&sumsq[cw + fn * 16 + fr], sq);
            }
        }
    }
}

// ---------------- BN column stats (vectorized two-level) ----------------
template <int M>
__global__ __launch_bounds__(256) void col_stats_fast(const u16* __restrict__ H,
                                                      float* __restrict__ sums,
                                                      float* __restrict__ sumsq, int nrows) {
    constexpr int C4 = M / 8;
    constexpr int RPB = 256 / C4;
    __shared__ float ls[M], lss[M];
    for (int j = threadIdx.x; j < M; j += 256) { ls[j] = 0.f; lss[j] = 0.f; }
    __syncthreads();
    const int c = threadIdx.x % C4;
    const int rg = threadIdx.x / C4;
    float s[8] = {}, ss[8] = {};
    const uint4* H4 = (const uint4*)H;
    for (int r = blockIdx.x * RPB + rg; r < nrows; r += gridDim.x * RPB) {
        uint4 v = H4[(size_t)r * C4 + c];
        float x0, x1, x2, x3, x4, x5, x6, x7;
        bf2(v.x, x0, x1); bf2(v.y, x2, x3); bf2(v.z, x4, x5); bf2(v.w, x6, x7);
        s[0] += x0; ss[0] += x0 * x0;  s[1] += x1; ss[1] += x1 * x1;
        s[2] += x2; ss[2] += x2 * x2;  s[3] += x3; ss[3] += x3 * x3;
        s[4] += x4; ss[4] += x4 * x4;  s[5] += x5; ss[5] += x5 * x5;
        s[6] += x6; ss[6] += x6 * x6;  s[7] += x7; ss[7] += x7 * x7;
    }
#pragma unroll
    for (int j = 0; j < 8; ++j) {
        atomicAdd(&ls[c * 8 + j], s[j]);
        atomicAdd(&lss[c * 8 + j], ss[j]);
    }
    __syncthreads();
    for (int j = threadIdx.x; j < M; j += 256) {
        atomicAdd(&sums[j], ls[j]);
        atomicAdd(&sumsq[j], lss[j]);
    }
}

// ---------------- BN finalize ----------------
template <int M>
__global__ void bn_finalize(const float* __restrict__ sums, const float* __restrict__ sumsq,
                            const float* __restrict__ g, const float* __restrict__ beta,
                            float* __restrict__ scale, float* __restrict__ shift, int nrows) {
    int j = threadIdx.x;
    if (j >= M) return;
    float mean = sums[j] / nrows;
    float var = fmaxf(sumsq[j] / nrows - mean * mean, 0.f);
    float sc = g[j] * rsqrtf(var + BN_EPS);
    scale[j] = sc;
    shift[j] = beta[j] - mean * sc;
}

// ---------------- head with fused BN3+ReLU: out = relu(bn(h3pre)) @ wh + bh ----------------
__global__ __launch_bounds__(256) void head_bn(const u16* __restrict__ H3pre,
                                               const float* __restrict__ sc,
                                               const float* __restrict__ sh,
                                               const float* __restrict__ wh,
                                               const float* __restrict__ bh,
                                               float* __restrict__ out, int n) {
    int i = blockIdx.x * blockDim.x + threadIdx.x;
    if (i >= n) return;
    const uint4* h4 = (const uint4*)(H3pre + (size_t)i * 64);
    float acc = bh[0];
#pragma unroll
    for (int c = 0; c < 8; ++c) {
        uint4 v = h4[c];
        float x0, x1, x2, x3, x4, x5, x6, x7;
        bf2(v.x, x0, x1); bf2(v.y, x2, x3); bf2(v.z, x4, x5); bf2(v.w, x6, x7);
        const float* s = sc + c * 8;
        const float* t = sh + c * 8;
        const float* w = wh + c * 8;
        acc += fmaxf(fmaf(x0, s[0], t[0]), 0.f) * w[0];
        acc += fmaxf(fmaf(x1, s[1], t[1]), 0.f) * w[1];
        acc += fmaxf(fmaf(x2, s[2], t[2]), 0.f) * w[2];
        acc += fmaxf(fmaf(x3, s[3], t[3]), 0.f) * w[3];
        acc += fmaxf(fmaf(x4, s[4], t[4]), 0.f) * w[4];
        acc += fmaxf(fmaf(x5, s[5], t[5]), 0.f) * w[5];
        acc += fmaxf(fmaf(x6, s[6], t[6]), 0.f) * w[6];
        acc += fmaxf(fmaf(x7, s[7], t[7]), 0.f) * w[7];
    }
    out[i] = acc;
}

// ---------------- launch ----------------
extern "C" void kernel_launch(void* const* d_in, const int* in_sizes, int n_in,
                              void* d_out, int out_size, void* d_ws, size_t ws_size,
                              hipStream_t stream) {
    const int N = N_NODES, E = N_EDGES;
    const float* x   = (const float*)d_in[0];
    const int*   ei  = (const int*)d_in[1];
    const int*   src = ei;
    const int*   dst = ei + E;
    const float* w1l = (const float*)d_in[2];
    const float* b1l = (const float*)d_in[3];
    const float* w1r = (const float*)d_in[4];
    const float* g1  = (const float*)d_in[5];
    const float* be1 = (const float*)d_in[6];
    const float* w2l = (const float*)d_in[7];
    const float* b2l = (const float*)d_in[8];
    const float* w2r = (const float*)d_in[9];
    const float* g2  = (const float*)d_in[10];
    const float* be2 = (const float*)d_in[11];
    const float* w3l = (const float*)d_in[12];
    const float* b3l = (const float*)d_in[13];
    const float* w3r = (const float*)d_in[14];
    const float* g3  = (const float*)d_in[15];
    const float* be3 = (const float*)d_in[16];
    const float* wh  = (const float*)d_in[17];
    const float* bh  = (const float*)d_in[18];
    float* out = (float*)d_out;

    // ---- workspace layout ----
    char* base = (char*)d_ws;
    size_t off = 0;
    auto alloc = [&](size_t bytes) -> void* {
        void* r = base + off;
        off += (bytes + 255) & ~(size_t)255;
        return r;
    };
    const int NB = (N + 255) / 256;  // 196
    int*   rowptr = (int*)alloc((N + 8) * sizeof(int));
    int*   csr    = (int*)alloc((size_t)E * sizeof(int));
    int*   deg_i  = (int*)alloc(N * sizeof(int));
    int*   cursor = (int*)alloc(N * sizeof(int));
    int*   bsum   = (int*)alloc(256 * sizeof(int));
    float* inv    = (float*)alloc(N * sizeof(float));
    u16*   xb     = (u16*)alloc((size_t)NP * 256 * 2);
    u16*   sB     = (u16*)alloc((size_t)NP * 256 * 2);
    u16*   hpre1  = (u16*)alloc((size_t)NP * 256 * 2);
    u16*   hpre2  = (u16*)alloc((size_t)NP * 256 * 2);   // [P|Q] layer 2
    u16*   h2pre  = (u16*)alloc((size_t)NP * 128 * 2);
    u16*   hpre3  = (u16*)alloc((size_t)NP * 128 * 2);   // [P|Q] layer 3
    u16*   h3pre  = (u16*)alloc((size_t)NP * 64 * 2);
    u16*   wt1    = (u16*)alloc((size_t)131072 * 2);
    u16*   wt2    = (u16*)alloc((size_t)65536 * 2);
    u16*   wt3    = (u16*)alloc((size_t)16384 * 2);
    float* stats  = (float*)alloc(1792 * sizeof(float));
    float* bias2  = (float*)alloc(256 * sizeof(float));
    float* bias3  = (float*)alloc(128 * sizeof(float));
    float* sums1 = stats,        *sumsq1 = stats + 256;
    float* sums2 = stats + 512,  *sumsq2 = stats + 640;
    float* sums3 = stats + 768,  *sumsq3 = stats + 832;
    float* scale1 = stats + 896,  *shift1 = stats + 1152;
    float* scale2 = stats + 1408, *shift2 = stats + 1536;
    float* scale3 = stats + 1664, *shift3 = stats + 1728;

    const int MB = NP / 128;  // 391

    // prep: x -> bf16 (+ zero deg)
    f32_to_bf16_zero<<<2048, 256, 0, stream>>>(x, xb, N * 256 / 8, deg_i, N / 4);

    // CSR build
    deg_count<<<(E + 255) / 256, 256, 0, stream>>>(dst, deg_i, E);
    scan_phase1<<<NB, 256, 0, stream>>>(deg_i, rowptr, bsum, N);
    scan_phase2<<<1, 256, 0, stream>>>(bsum, rowptr, stats, 896, NB, N);
    scan_phase3<<<NB, 256, 0, stream>>>(rowptr, bsum, deg_i, inv, cursor, N);
    csr_fill<<<(E + 255) / 256, 256, 0, stream>>>(src, dst, rowptr, cursor, csr, E);

    // weights
    prep_weights<<<(131072 + 65536 + 16384 + 384 + 255) / 256, 256, 0, stream>>>(
        w1l, w1r, w2l, w2r, w3l, w3r, b2l, b3l, wt1, wt2, wt3, bias2, bias3);

    // layer 1: agg-first, [S|X] K=512 -> 256, stats fused
    gather_mean_bf16<256><<<(N * 32 + 255) / 256, 256, 0, stream>>>(xb, rowptr, csr, inv, sB, N);
    sage_gemm<256, 512, 256, true, false><<<MB, 256, 0, stream>>>(
        sB, xb, wt1, b1l, nullptr, nullptr, hpre1, sums1, sumsq1, N);
    bn_finalize<256><<<1, 256, 0, stream>>>(sums1, sumsq1, g1, be1, scale1, shift1, N);

    // layer 2: transform-first, BN1+ReLU fused into A staging
    sage_gemm<256, 256, 256, false, true><<<MB, 256, 0, stream>>>(
        hpre1, hpre1, wt2, bias2, scale1, shift1, hpre2, nullptr, nullptr, N);
    gather_add_bf16<128><<<(N * 16 + 255) / 256, 256, 0, stream>>>(hpre2, rowptr, csr, inv, h2pre, N);
    col_stats_fast<128><<<256, 256, 0, stream>>>(h2pre, sums2, sumsq2, N);
    bn_finalize<128><<<1, 128, 0, stream>>>(sums2, sumsq2, g2, be2, scale2, shift2, N);

    // layer 3: transform-first, BN2+ReLU fused into A staging
    sage_gemm<128, 128, 128, false, true><<<MB, 256, 0, stream>>>(
        h2pre, h2pre, wt3, bias3, scale2, shift2, hpre3, nullptr, nullptr, N);
    gather_add_bf16<64><<<(N * 8 + 255) / 256, 256, 0, stream>>>(hpre3, rowptr, csr, inv, h3pre, N);
    col_stats_fast<64><<<256, 256, 0, stream>>>(h3pre, sums3, sumsq3, N);
    bn_finalize<64><<<1, 64, 0, stream>>>(sums3, sumsq3, g3, be3, scale3, shift3, N);

    // head with fused BN3+ReLU
    head_bn<<<(N + 255) / 256, 256, 0, stream>>>(h3pre, scale3, shift3, wh, bh, out, N);
}